// Round 7
// baseline (428.218 us; speedup 1.0000x reference)
//
#include <hip/hip_runtime.h>
#include <hip/hip_fp16.h>

#define DB    768
#define SEQ   2048
#define BATCH 8
#define NTOK  (BATCH*SEQ)      // 16384
#define NFUSE (3*DB)           // 2304 fused QKV output columns
#define NORM_F 0.036084391824351613f
#define ASCALE 512.0f          // attn stored *512 in fp16 to dodge denorm flush
#define INV_ASCALE (1.0f/512.0f)

typedef __attribute__((ext_vector_type(8))) short    short8;
typedef __attribute__((ext_vector_type(8))) _Float16 half8;
typedef __attribute__((ext_vector_type(4))) float    f32x4;
typedef __attribute__((ext_vector_type(4))) float    float4v;
typedef unsigned int u32;

__device__ __forceinline__ float h2f_bits(unsigned short h) {
  __half v; __builtin_memcpy(&v, &h, 2); return __half2float(v);
}
__device__ __forceinline__ unsigned short f2h_bits(float f) {
  __half v = __float2half(f); unsigned short u; __builtin_memcpy(&u, &v, 2); return u;
}

// async global->LDS, 16B/lane. LDS dest = wave-uniform base + lane*16.
__device__ __forceinline__ void glds16(const unsigned short* g, void* l) {
  __builtin_amdgcn_global_load_lds(
      (const __attribute__((address_space(1))) u32*)(const void*)g,
      (__attribute__((address_space(3))) u32*)l, 16, 0, 0);
}

// Chunk-major 128x32 fp16 tile in LDS: element (row, c*8+e) at short index
// c*1024 + row*8 + e.  glds-linear (wave w issue j covers c=j*2+(w>>1),
// rows (w&1)*64..+63) and conflict-free ds_read_b128 fragment reads
// (8 consecutive lanes cover all 32 banks).

// =============================================================================
// whalf: W[d][n] (3 weights) -> fused WT[nf][d] fp16, via LDS transpose.
// =============================================================================
__global__ __launch_bounds__(256) void whalf_kernel(
    const float* __restrict__ Wq, const float* __restrict__ Wk,
    const float* __restrict__ Wv, unsigned short* __restrict__ WT) {
  __shared__ float T[64][68];
  int bx = blockIdx.x;
  int w = bx / 144, rem = bx % 144;
  int d0 = (rem / 12) * 64, n0 = (rem % 12) * 64;
  const float* W = (w == 0) ? Wq : ((w == 1) ? Wk : Wv);
  int t = threadIdx.x;
  int dl = t >> 4, n4 = (t & 15) * 4;
#pragma unroll
  for (int j = 0; j < 4; j++) {
    float4v v = *(const float4v*)(W + (size_t)(d0 + dl + j * 16) * DB + n0 + n4);
    *(float4v*)&T[dl + j * 16][n4] = v;
  }
  __syncthreads();
  int nl = t >> 2, dc = (t & 3) * 16;
  short8 hb[2];
#pragma unroll
  for (int e = 0; e < 16; e++)
    hb[e >> 3][e & 7] = (short)f2h_bits(T[dc + e][nl]);
  size_t o = ((size_t)w * DB + n0 + nl) * DB + d0 + dc;
  *(short8*)(WT + o) = hb[0]; *(short8*)(WT + o + 8) = hb[1];
}

// =============================================================================
// xhalf: X fp32 -> Xf fp16.
// =============================================================================
__global__ __launch_bounds__(256) void xhalf_kernel(
    const float* __restrict__ X, unsigned short* __restrict__ Xf) {
  size_t i8 = ((size_t)blockIdx.x * 256 + threadIdx.x) * 8;
  float4v v0 = *(const float4v*)(X + i8);
  float4v v1 = *(const float4v*)(X + i8 + 4);
  short8 h;
#pragma unroll
  for (int j = 0; j < 4; j++) h[j] = (short)f2h_bits(v0[j]);
#pragma unroll
  for (int j = 0; j < 4; j++) h[4 + j] = (short)f2h_bits(v1[j]);
  *(short8*)(Xf + i8) = h;
}

// =============================================================================
// compact: per batch, list of unmasked q indices (ascending) + count.
// =============================================================================
__global__ __launch_bounds__(256) void compact_kernel(
    const int* __restrict__ mask, int* __restrict__ idx, int* __restrict__ cnt) {
  int b = blockIdx.x, t = threadIdx.x;
  const int* m = mask + b * SEQ;
  __shared__ int pref[256];
  int mv[8], c = 0, base = t * 8;
#pragma unroll
  for (int j = 0; j < 8; j++) { mv[j] = (m[base + j] != 0); c += mv[j]; }
  pref[t] = c;
  __syncthreads();
  for (int off = 1; off < 256; off <<= 1) {
    int add = (t >= off) ? pref[t - off] : 0;
    __syncthreads();
    pref[t] += add;
    __syncthreads();
  }
  int o = pref[t] - c;
  int* ib = idx + b * SEQ;
#pragma unroll
  for (int j = 0; j < 8; j++) if (mv[j]) ib[o++] = base + j;
  if (t == 255) cnt[b] = pref[255];
}

// =============================================================================
// proj: fused QKV GEMM, fp16 MFMA, m97-style glds16 staging (2-barrier K-loop,
// chunk-major LDS, 16 KB single-buffered).  XCD swizzle: xcd g owns batch g.
// =============================================================================
__global__ __launch_bounds__(256) void proj_kernel(
    const unsigned short* __restrict__ Xf, const unsigned short* __restrict__ WT,
    const float* __restrict__ bq, const float* __restrict__ bk,
    const float* __restrict__ bv,
    unsigned short* __restrict__ Qf, unsigned short* __restrict__ Kf,
    unsigned short* __restrict__ VT) {
  __shared__ __align__(16) unsigned short As[8192], Bs[8192];   // 16 KB
  int L = blockIdx.x;
  int g = L & 7, tt = L >> 3;                 // 2304 blocks: 288 per xcd
  int m0 = (g * 16 + (tt & 15)) << 7;         // batch-g rows
  int n0 = (tt >> 4) << 7;                    // n outer
  int tid = threadIdx.x;
  int wave = tid >> 6, lane = tid & 63;
  int wm = wave & 1, wn = wave >> 1;
  int quad = lane >> 4, l16 = lane & 15;
  int srow = ((wave & 1) << 6) | lane;        // staged row
  int coff = (wave >> 1) * 8;                 // k-chunk offset, issue 0

  const unsigned short* pA = Xf + (size_t)(m0 + srow) * DB + coff;
  const unsigned short* pB = WT + (size_t)(n0 + srow) * DB + coff;
  char* lA = (char*)As + wave * 1024;
  char* lB = (char*)Bs + wave * 1024;

  f32x4 acc[4][4];
#pragma unroll
  for (int mi = 0; mi < 4; mi++)
#pragma unroll
    for (int ni = 0; ni < 4; ni++) acc[mi][ni] = (f32x4){0.f, 0.f, 0.f, 0.f};

  for (int it = 0; it < 24; it++) {
    int kt = it * 32;
    glds16(pA + kt, lA);  glds16(pA + kt + 16, lA + 4096);
    glds16(pB + kt, lB);  glds16(pB + kt + 16, lB + 4096);
    __builtin_amdgcn_s_waitcnt(0);
    __syncthreads();

    half8 af[4], bfr[4];
#pragma unroll
    for (int mi = 0; mi < 4; mi++)
      af[mi] = *(const half8*)&As[quad * 1024 + (wm * 64 + mi * 16 + l16) * 8];
#pragma unroll
    for (int ni = 0; ni < 4; ni++)
      bfr[ni] = *(const half8*)&Bs[quad * 1024 + (wn * 64 + ni * 16 + l16) * 8];
#pragma unroll
    for (int mi = 0; mi < 4; mi++)
#pragma unroll
      for (int ni = 0; ni < 4; ni++)
        acc[mi][ni] = __builtin_amdgcn_mfma_f32_16x16x32_f16(af[mi], bfr[ni], acc[mi][ni], 0, 0, 0);
    __syncthreads();
  }

  int z = n0 / DB;                 // 0=Q 1=K 2=V, block-uniform
  int nl0 = n0 - z * DB;
  const float* bias = (z == 0) ? bq : ((z == 1) ? bk : bv);
#pragma unroll
  for (int mi = 0; mi < 4; mi++)
#pragma unroll
    for (int ni = 0; ni < 4; ni++)
#pragma unroll
      for (int r = 0; r < 4; r++) {
        int gm = m0 + wm * 64 + mi * 16 + quad * 4 + r;
        int ln = nl0 + wn * 64 + ni * 16 + l16;
        unsigned short h = f2h_bits(acc[mi][ni][r] + bias[ln]);
        if (z == 0) {
          Qf[(size_t)gm * DB + ln] = h;
        } else if (z == 1) {
          Kf[(size_t)gm * DB + ln] = h;
        } else {
          int bb = gm >> 11, s = gm & 2047;
          VT[((size_t)bb * DB + ln) * SEQ + s] = h;
        }
      }
}

// =============================================================================
// vmean: Vmean[b][n] = mean_s VT[b][n][s]  (VT fp16).
// =============================================================================
__global__ __launch_bounds__(256) void vmean_kernel(
    const unsigned short* __restrict__ VT, float* __restrict__ Vmean) {
  int bn = blockIdx.x;
  const unsigned short* p = VT + (size_t)bn * SEQ;
  int t = threadIdx.x, wave = t >> 6, lane = t & 63;
  short8 hv = *(const short8*)(p + t * 8);
  float s = 0.f;
#pragma unroll
  for (int j = 0; j < 8; j++) s += h2f_bits((unsigned short)hv[j]);
#pragma unroll
  for (int off = 32; off >= 1; off >>= 1) s += __shfl_down(s, off);
  __shared__ float red[4];
  if (lane == 0) red[wave] = s;
  __syncthreads();
  if (t == 0) Vmean[bn] = (red[0] + red[1] + red[2] + red[3]) * (1.0f / SEQ);
}

// =============================================================================
// scores (compacted q): SC[b][qc][t] = Qf[idx[qc]] . Kf[t], fp16 in/out.
// glds16 staging.  XCD swizzle: xcd g owns batch g (K(b) L2-resident).
// =============================================================================
__global__ __launch_bounds__(256) void scores_kernel(
    const unsigned short* __restrict__ Qf, const unsigned short* __restrict__ Kf,
    const int* __restrict__ idx, const int* __restrict__ cnt,
    unsigned short* __restrict__ SC) {
  __shared__ __align__(16) unsigned short As[8192], Bs[8192];
  int L = blockIdx.x;
  int b = L & 7, tt = L >> 3;                 // 2048 blocks: 256 per xcd
  int q0 = (tt >> 4) << 7;                    // q outer
  int t0 = (tt & 15) << 7;                    // t inner
  int cb = cnt[b];
  if (q0 >= cb) return;
  int tid = threadIdx.x;
  int wave = tid >> 6, lane = tid & 63;
  int wm = wave & 1, wn = wave >> 1;
  int quad = lane >> 4, l16 = lane & 15;
  int srow = ((wave & 1) << 6) | lane;
  int coff = (wave >> 1) * 8;

  int qr = q0 + srow; if (qr >= cb) qr = cb - 1;   // clamp tail (writes guarded)
  int gq = idx[b * SEQ + qr];
  const unsigned short* pA = Qf + ((size_t)b * SEQ + gq) * DB + coff;
  const unsigned short* pB = Kf + ((size_t)b * SEQ + t0 + srow) * DB + coff;
  char* lA = (char*)As + wave * 1024;
  char* lB = (char*)Bs + wave * 1024;

  f32x4 acc[4][4];
#pragma unroll
  for (int mi = 0; mi < 4; mi++)
#pragma unroll
    for (int ni = 0; ni < 4; ni++) acc[mi][ni] = (f32x4){0.f, 0.f, 0.f, 0.f};

  for (int it = 0; it < 24; it++) {
    int kt = it * 32;
    glds16(pA + kt, lA);  glds16(pA + kt + 16, lA + 4096);
    glds16(pB + kt, lB);  glds16(pB + kt + 16, lB + 4096);
    __builtin_amdgcn_s_waitcnt(0);
    __syncthreads();

    half8 af[4], bfr[4];
#pragma unroll
    for (int mi = 0; mi < 4; mi++)
      af[mi] = *(const half8*)&As[quad * 1024 + (wm * 64 + mi * 16 + l16) * 8];
#pragma unroll
    for (int ni = 0; ni < 4; ni++)
      bfr[ni] = *(const half8*)&Bs[quad * 1024 + (wn * 64 + ni * 16 + l16) * 8];
#pragma unroll
    for (int mi = 0; mi < 4; mi++)
#pragma unroll
      for (int ni = 0; ni < 4; ni++)
        acc[mi][ni] = __builtin_amdgcn_mfma_f32_16x16x32_f16(af[mi], bfr[ni], acc[mi][ni], 0, 0, 0);
    __syncthreads();
  }

#pragma unroll
  for (int mi = 0; mi < 4; mi++)
#pragma unroll
    for (int r = 0; r < 4; r++) {
      int qc = q0 + wm * 64 + mi * 16 + quad * 4 + r;
      if (qc < cb) {
#pragma unroll
        for (int ni = 0; ni < 4; ni++) {
          int gt = t0 + wn * 64 + ni * 16 + l16;
          SC[((size_t)b * SEQ + qc) * SEQ + gt] = f2h_bits(acc[mi][ni][r]);
        }
      }
    }
}

// =============================================================================
// softmax on compacted rows: fp16 scores -> fp16 (softmax * NORM * ASCALE).
// =============================================================================
__global__ __launch_bounds__(256) void softmax_kernel(
    unsigned short* __restrict__ SC, const int* __restrict__ cnt) {
  int b = blockIdx.x >> 11, qc = blockIdx.x & 2047;
  if (qc >= cnt[b]) return;
  unsigned short* p = SC + ((size_t)b * SEQ + qc) * SEQ;
  int tid = threadIdx.x;

  short8 hv = *(const short8*)(p + (tid << 3));
  float v[8];
#pragma unroll
  for (int j = 0; j < 8; j++) v[j] = h2f_bits((unsigned short)hv[j]);

  float m = v[0];
#pragma unroll
  for (int j = 1; j < 8; j++) m = fmaxf(m, v[j]);
#pragma unroll
  for (int off = 32; off >= 1; off >>= 1) m = fmaxf(m, __shfl_down(m, off));

  __shared__ float red[8];
  int w = tid >> 6;
  if ((tid & 63) == 0) red[w] = m;
  __syncthreads();
  m = fmaxf(fmaxf(red[0], red[1]), fmaxf(red[2], red[3]));

  float e[8], s = 0.f;
#pragma unroll
  for (int j = 0; j < 8; j++) { e[j] = __expf(v[j] - m); s += e[j]; }
#pragma unroll
  for (int off = 32; off >= 1; off >>= 1) s += __shfl_down(s, off);
  if ((tid & 63) == 0) red[4 + w] = s;
  __syncthreads();
  float L = red[4] + red[5] + red[6] + red[7];

  float scale = NORM_F * ASCALE / L;   // ASCALE undone in pv epilogue
  short8 ov;
#pragma unroll
  for (int j = 0; j < 8; j++) ov[j] = (short)f2h_bits(e[j] * scale);
  *(short8*)(p + (tid << 3)) = ov;
}

// =============================================================================
// fill: masked rows get NORM * mean(V).
// =============================================================================
__global__ __launch_bounds__(256) void fill_kernel(
    const int* __restrict__ mask, const float* __restrict__ Vmean,
    float* __restrict__ out) {
  int row = blockIdx.x;
  if (mask[row] != 0) return;
  const float* vm = Vmean + (row >> 11) * DB;
  float* o = out + (size_t)row * DB;
  for (int n = threadIdx.x; n < DB; n += 256) o[n] = vm[n] * NORM_F;
}

// =============================================================================
// pv (compacted): out[idx[qc]][v] = (1/ASCALE) * sum_t attn[qc][t] * V[t][v].
// glds16 staging.  XCD swizzle: xcd g owns batch g (VT(b) L2-resident).
// =============================================================================
__global__ __launch_bounds__(256) void pv_kernel(
    const unsigned short* __restrict__ SC, const unsigned short* __restrict__ VT,
    const int* __restrict__ idx, const int* __restrict__ cnt,
    float* __restrict__ out) {
  __shared__ __align__(16) unsigned short As[8192], Bs[8192];
  int L = blockIdx.x;
  int b = L & 7, tt = L >> 3;                 // 768 blocks: 96 per xcd
  int q0 = (tt / 6) << 7;                     // q outer
  int v0 = (tt % 6) << 7;                     // v inner (SC stripe reused 6x)
  int cb = cnt[b];
  if (q0 >= cb) return;
  int tid = threadIdx.x;
  int wave = tid >> 6, lane = tid & 63;
  int wm = wave & 1, wn = wave >> 1;
  int quad = lane >> 4, l16 = lane & 15;
  int srow = ((wave & 1) << 6) | lane;
  int coff = (wave >> 1) * 8;

  const unsigned short* pA = SC + ((size_t)b * SEQ + q0 + srow) * SEQ + coff;  // rows>=cb: garbage, guarded
  const unsigned short* pB = VT + ((size_t)b * DB + v0 + srow) * SEQ + coff;
  char* lA = (char*)As + wave * 1024;
  char* lB = (char*)Bs + wave * 1024;

  f32x4 acc[4][4];
#pragma unroll
  for (int mi = 0; mi < 4; mi++)
#pragma unroll
    for (int ni = 0; ni < 4; ni++) acc[mi][ni] = (f32x4){0.f, 0.f, 0.f, 0.f};

  for (int it = 0; it < 64; it++) {
    int kt = it * 32;
    glds16(pA + kt, lA);  glds16(pA + kt + 16, lA + 4096);
    glds16(pB + kt, lB);  glds16(pB + kt + 16, lB + 4096);
    __builtin_amdgcn_s_waitcnt(0);
    __syncthreads();

    half8 af[4], bfr[4];
#pragma unroll
    for (int mi = 0; mi < 4; mi++)
      af[mi] = *(const half8*)&As[quad * 1024 + (wm * 64 + mi * 16 + l16) * 8];
#pragma unroll
    for (int ni = 0; ni < 4; ni++)
      bfr[ni] = *(const half8*)&Bs[quad * 1024 + (wn * 64 + ni * 16 + l16) * 8];
#pragma unroll
    for (int mi = 0; mi < 4; mi++)
#pragma unroll
      for (int ni = 0; ni < 4; ni++)
        acc[mi][ni] = __builtin_amdgcn_mfma_f32_16x16x32_f16(af[mi], bfr[ni], acc[mi][ni], 0, 0, 0);
    __syncthreads();
  }

#pragma unroll
  for (int mi = 0; mi < 4; mi++)
#pragma unroll
    for (int r = 0; r < 4; r++) {
      int qc = q0 + wm * 64 + mi * 16 + quad * 4 + r;
      if (qc < cb) {
        int q = idx[b * SEQ + qc];
#pragma unroll
        for (int ni = 0; ni < 4; ni++) {
          int gv = v0 + wn * 64 + ni * 16 + l16;
          out[((size_t)b * SEQ + q) * DB + gv] = acc[mi][ni][r] * INV_ASCALE;
        }
      }
    }
}

// =============================================================================
extern "C" void kernel_launch(void* const* d_in, const int* in_sizes, int n_in,
                              void* d_out, int out_size, void* d_ws, size_t ws_size,
                              hipStream_t stream) {
  const float* x    = (const float*)d_in[0];
  const int*   mask = (const int*)d_in[1];
  const float* Wq   = (const float*)d_in[2];
  const float* bq   = (const float*)d_in[3];
  const float* Wk   = (const float*)d_in[4];
  const float* bk   = (const float*)d_in[5];
  const float* Wv   = (const float*)d_in[6];
  const float* bv   = (const float*)d_in[7];
  float* out = (float*)d_out;
  char* ws = (char*)d_ws;

  // Workspace (~143 MB). SC region [0, 67.1MB) also hosts Xf/WT, which die
  // when proj completes; scores then overwrites with SC.
  const size_t TOKH = (size_t)NTOK * DB * 2;                 // 25,165,824 B
  unsigned short* SC = (unsigned short*)ws;
  unsigned short* Xf = (unsigned short*)ws;
  unsigned short* WT = (unsigned short*)(ws + TOKH);
  const size_t SCSZ = (size_t)BATCH * SEQ * SEQ * 2;         // 67,108,864 B
  unsigned short* Qf = (unsigned short*)(ws + SCSZ);
  unsigned short* Kf = Qf + (size_t)NTOK * DB;
  unsigned short* VT = Kf + (size_t)NTOK * DB;
  int*   idx   = (int*)(ws + SCSZ + 3 * TOKH);
  int*   cnt   = idx + NTOK;
  float* Vmean = (float*)(cnt + 16);

  whalf_kernel<<<432, 256, 0, stream>>>(Wq, Wk, Wv, WT);
  xhalf_kernel<<<NTOK * DB / 2048, 256, 0, stream>>>(x, Xf);
  compact_kernel<<<BATCH, 256, 0, stream>>>(mask, idx, cnt);
  proj_kernel<<<NFUSE / 128 * (NTOK / 128), 256, 0, stream>>>(
      Xf, WT, bq, bk, bv, Qf, Kf, VT);
  vmean_kernel<<<BATCH * DB, 256, 0, stream>>>(VT, Vmean);
  scores_kernel<<<(SEQ / 128) * (SEQ / 128) * BATCH, 256, 0, stream>>>(
      Qf, Kf, idx, cnt, SC);
  softmax_kernel<<<NTOK, 256, 0, stream>>>(SC, cnt);
  fill_kernel<<<NTOK, 256, 0, stream>>>(mask, Vmean, out);
  pv_kernel<<<(DB / 128) * (SEQ / 128) * BATCH, 256, 0, stream>>>(
      SC, VT, idx, cnt, out);
}

// Round 8
// 424.000 us; speedup vs baseline: 1.0099x; 1.0099x over previous
//
#include <hip/hip_runtime.h>
#include <hip/hip_fp16.h>

#define DB    768
#define SEQ   2048
#define BATCH 8
#define NTOK  (BATCH*SEQ)      // 16384
#define NFUSE (3*DB)           // 2304 fused QKV output columns
#define NORM_F 0.036084391824351613f
#define ASCALE 512.0f          // attn stored *512 in fp16 to dodge denorm flush
#define INV_ASCALE (1.0f/512.0f)

typedef __attribute__((ext_vector_type(8))) short    short8;
typedef __attribute__((ext_vector_type(8))) _Float16 half8;
typedef __attribute__((ext_vector_type(4))) float    f32x4;
typedef __attribute__((ext_vector_type(4))) float    float4v;

__device__ __forceinline__ float h2f_bits(unsigned short h) {
  __half v; __builtin_memcpy(&v, &h, 2); return __half2float(v);
}
__device__ __forceinline__ unsigned short f2h_bits(float f) {
  __half v = __float2half(f); unsigned short u; __builtin_memcpy(&u, &v, 2); return u;
}

// Chunk-major 128x32 fp16 tile in LDS (8 KB): element (row, c*8+e) at short
// index c*1024 + row*8 + e.  Staging: thread (wave w, lane l, issue j) loads
// global row (w&1)*64+l, k-chunk j*2+(w>>1), and ds_write_b128's it to byte
// offset w*1024 + l*16 + j*4096 — linear banks (0 conflicts, measured R7).
// Frag reads quad*1024 + row*8 measured conflict-free (R7).

// =============================================================================
// whalf: W[d][n] (3 weights) -> fused WT[nf][d] fp16, via LDS transpose.
// =============================================================================
__global__ __launch_bounds__(256) void whalf_kernel(
    const float* __restrict__ Wq, const float* __restrict__ Wk,
    const float* __restrict__ Wv, unsigned short* __restrict__ WT) {
  __shared__ float T[64][68];
  int bx = blockIdx.x;
  int w = bx / 144, rem = bx % 144;
  int d0 = (rem / 12) * 64, n0 = (rem % 12) * 64;
  const float* W = (w == 0) ? Wq : ((w == 1) ? Wk : Wv);
  int t = threadIdx.x;
  int dl = t >> 4, n4 = (t & 15) * 4;
#pragma unroll
  for (int j = 0; j < 4; j++) {
    float4v v = *(const float4v*)(W + (size_t)(d0 + dl + j * 16) * DB + n0 + n4);
    *(float4v*)&T[dl + j * 16][n4] = v;
  }
  __syncthreads();
  int nl = t >> 2, dc = (t & 3) * 16;
  short8 hb[2];
#pragma unroll
  for (int e = 0; e < 16; e++)
    hb[e >> 3][e & 7] = (short)f2h_bits(T[dc + e][nl]);
  size_t o = ((size_t)w * DB + n0 + nl) * DB + d0 + dc;
  *(short8*)(WT + o) = hb[0]; *(short8*)(WT + o + 8) = hb[1];
}

// =============================================================================
// xhalf: X fp32 -> Xf fp16.
// =============================================================================
__global__ __launch_bounds__(256) void xhalf_kernel(
    const float* __restrict__ X, unsigned short* __restrict__ Xf) {
  size_t i8 = ((size_t)blockIdx.x * 256 + threadIdx.x) * 8;
  float4v v0 = *(const float4v*)(X + i8);
  float4v v1 = *(const float4v*)(X + i8 + 4);
  short8 h;
#pragma unroll
  for (int j = 0; j < 4; j++) h[j] = (short)f2h_bits(v0[j]);
#pragma unroll
  for (int j = 0; j < 4; j++) h[4 + j] = (short)f2h_bits(v1[j]);
  *(short8*)(Xf + i8) = h;
}

// =============================================================================
// compact: per batch, list of unmasked q indices (ascending) + count.
// =============================================================================
__global__ __launch_bounds__(256) void compact_kernel(
    const int* __restrict__ mask, int* __restrict__ idx, int* __restrict__ cnt) {
  int b = blockIdx.x, t = threadIdx.x;
  const int* m = mask + b * SEQ;
  __shared__ int pref[256];
  int mv[8], c = 0, base = t * 8;
#pragma unroll
  for (int j = 0; j < 8; j++) { mv[j] = (m[base + j] != 0); c += mv[j]; }
  pref[t] = c;
  __syncthreads();
  for (int off = 1; off < 256; off <<= 1) {
    int add = (t >= off) ? pref[t - off] : 0;
    __syncthreads();
    pref[t] += add;
    __syncthreads();
  }
  int o = pref[t] - c;
  int* ib = idx + b * SEQ;
#pragma unroll
  for (int j = 0; j < 8; j++) if (mv[j]) ib[o++] = base + j;
  if (t == 255) cnt[b] = pref[255];
}

// =============================================================================
// proj: fused QKV GEMM, fp16 MFMA.  VGPR round-trip staging with prefetch
// (R6 structure) + chunk-major conflict-free LDS (R7 layout).
// XCD swizzle: xcd g owns batch g's m-stripe; n outer.
// =============================================================================
__global__ __launch_bounds__(256) void proj_kernel(
    const unsigned short* __restrict__ Xf, const unsigned short* __restrict__ WT,
    const float* __restrict__ bq, const float* __restrict__ bk,
    const float* __restrict__ bv,
    unsigned short* __restrict__ Qf, unsigned short* __restrict__ Kf,
    unsigned short* __restrict__ VT) {
  __shared__ __align__(16) unsigned short As[8192], Bs[8192];   // 16 KB
  int L = blockIdx.x;
  int g = L & 7, tt = L >> 3;                 // 2304 blocks: 288 per xcd
  int m0 = (g * 16 + (tt & 15)) << 7;         // batch-g rows
  int n0 = (tt >> 4) << 7;                    // n outer
  int tid = threadIdx.x;
  int wave = tid >> 6, lane = tid & 63;
  int wm = wave & 1, wn = wave >> 1;
  int quad = lane >> 4, l16 = lane & 15;
  int srow = ((wave & 1) << 6) | lane;        // staged row
  int coff = (wave >> 1) * 8;                 // k-chunk offset, issue 0

  const unsigned short* pA = Xf + (size_t)(m0 + srow) * DB + coff;
  const unsigned short* pB = WT + (size_t)(n0 + srow) * DB + coff;
  unsigned short* lA = (unsigned short*)((char*)As + wave * 1024 + lane * 16);
  unsigned short* lB = (unsigned short*)((char*)Bs + wave * 1024 + lane * 16);

  f32x4 acc[4][4];
#pragma unroll
  for (int mi = 0; mi < 4; mi++)
#pragma unroll
    for (int ni = 0; ni < 4; ni++) acc[mi][ni] = (f32x4){0.f, 0.f, 0.f, 0.f};

  short8 va[2], vb[2];
  auto gld = [&](int kt) {
    va[0] = *(const short8*)(pA + kt);  va[1] = *(const short8*)(pA + kt + 16);
    vb[0] = *(const short8*)(pB + kt);  vb[1] = *(const short8*)(pB + kt + 16);
  };

  gld(0);
  for (int it = 0; it < 24; it++) {
    __syncthreads();                      // prev iter's frag reads complete
    *(short8*)lA = va[0];  *(short8*)(lA + 2048) = va[1];
    *(short8*)lB = vb[0];  *(short8*)(lB + 2048) = vb[1];
    __syncthreads();
    if (it < 23) gld((it + 1) * 32);      // prefetch flies over the MFMAs

    half8 af[4], bfr[4];
#pragma unroll
    for (int mi = 0; mi < 4; mi++)
      af[mi] = *(const half8*)&As[quad * 1024 + (wm * 64 + mi * 16 + l16) * 8];
#pragma unroll
    for (int ni = 0; ni < 4; ni++)
      bfr[ni] = *(const half8*)&Bs[quad * 1024 + (wn * 64 + ni * 16 + l16) * 8];
#pragma unroll
    for (int mi = 0; mi < 4; mi++)
#pragma unroll
      for (int ni = 0; ni < 4; ni++)
        acc[mi][ni] = __builtin_amdgcn_mfma_f32_16x16x32_f16(af[mi], bfr[ni], acc[mi][ni], 0, 0, 0);
  }

  int z = n0 / DB;                 // 0=Q 1=K 2=V, block-uniform
  int nl0 = n0 - z * DB;
  const float* bias = (z == 0) ? bq : ((z == 1) ? bk : bv);
#pragma unroll
  for (int mi = 0; mi < 4; mi++)
#pragma unroll
    for (int ni = 0; ni < 4; ni++)
#pragma unroll
      for (int r = 0; r < 4; r++) {
        int gm = m0 + wm * 64 + mi * 16 + quad * 4 + r;
        int ln = nl0 + wn * 64 + ni * 16 + l16;
        unsigned short h = f2h_bits(acc[mi][ni][r] + bias[ln]);
        if (z == 0) {
          Qf[(size_t)gm * DB + ln] = h;
        } else if (z == 1) {
          Kf[(size_t)gm * DB + ln] = h;
        } else {
          int bb = gm >> 11, s = gm & 2047;
          VT[((size_t)bb * DB + ln) * SEQ + s] = h;
        }
      }
}

// =============================================================================
// vmean: Vmean[b][n] = mean_s VT[b][n][s]  (VT fp16).
// =============================================================================
__global__ __launch_bounds__(256) void vmean_kernel(
    const unsigned short* __restrict__ VT, float* __restrict__ Vmean) {
  int bn = blockIdx.x;
  const unsigned short* p = VT + (size_t)bn * SEQ;
  int t = threadIdx.x, wave = t >> 6, lane = t & 63;
  short8 hv = *(const short8*)(p + t * 8);
  float s = 0.f;
#pragma unroll
  for (int j = 0; j < 8; j++) s += h2f_bits((unsigned short)hv[j]);
#pragma unroll
  for (int off = 32; off >= 1; off >>= 1) s += __shfl_down(s, off);
  __shared__ float red[4];
  if (lane == 0) red[wave] = s;
  __syncthreads();
  if (t == 0) Vmean[bn] = (red[0] + red[1] + red[2] + red[3]) * (1.0f / SEQ);
}

// =============================================================================
// scores (compacted q): SC[b][qc][t] = Qf[idx[qc]] . Kf[t], fp16 in/out.
// Same staging as proj.  XCD swizzle: xcd g owns batch g (K(b) L2-resident).
// =============================================================================
__global__ __launch_bounds__(256) void scores_kernel(
    const unsigned short* __restrict__ Qf, const unsigned short* __restrict__ Kf,
    const int* __restrict__ idx, const int* __restrict__ cnt,
    unsigned short* __restrict__ SC) {
  __shared__ __align__(16) unsigned short As[8192], Bs[8192];
  int L = blockIdx.x;
  int b = L & 7, tt = L >> 3;                 // 2048 blocks: 256 per xcd
  int q0 = (tt >> 4) << 7;                    // q outer
  int t0 = (tt & 15) << 7;                    // t inner
  int cb = cnt[b];
  if (q0 >= cb) return;
  int tid = threadIdx.x;
  int wave = tid >> 6, lane = tid & 63;
  int wm = wave & 1, wn = wave >> 1;
  int quad = lane >> 4, l16 = lane & 15;
  int srow = ((wave & 1) << 6) | lane;
  int coff = (wave >> 1) * 8;

  int qr = q0 + srow; if (qr >= cb) qr = cb - 1;   // clamp tail (writes guarded)
  int gq = idx[b * SEQ + qr];
  const unsigned short* pA = Qf + ((size_t)b * SEQ + gq) * DB + coff;
  const unsigned short* pB = Kf + ((size_t)b * SEQ + t0 + srow) * DB + coff;
  unsigned short* lA = (unsigned short*)((char*)As + wave * 1024 + lane * 16);
  unsigned short* lB = (unsigned short*)((char*)Bs + wave * 1024 + lane * 16);

  f32x4 acc[4][4];
#pragma unroll
  for (int mi = 0; mi < 4; mi++)
#pragma unroll
    for (int ni = 0; ni < 4; ni++) acc[mi][ni] = (f32x4){0.f, 0.f, 0.f, 0.f};

  short8 va[2], vb[2];
  auto gld = [&](int kt) {
    va[0] = *(const short8*)(pA + kt);  va[1] = *(const short8*)(pA + kt + 16);
    vb[0] = *(const short8*)(pB + kt);  vb[1] = *(const short8*)(pB + kt + 16);
  };

  gld(0);
  for (int it = 0; it < 24; it++) {
    __syncthreads();
    *(short8*)lA = va[0];  *(short8*)(lA + 2048) = va[1];
    *(short8*)lB = vb[0];  *(short8*)(lB + 2048) = vb[1];
    __syncthreads();
    if (it < 23) gld((it + 1) * 32);

    half8 af[4], bfr[4];
#pragma unroll
    for (int mi = 0; mi < 4; mi++)
      af[mi] = *(const half8*)&As[quad * 1024 + (wm * 64 + mi * 16 + l16) * 8];
#pragma unroll
    for (int ni = 0; ni < 4; ni++)
      bfr[ni] = *(const half8*)&Bs[quad * 1024 + (wn * 64 + ni * 16 + l16) * 8];
#pragma unroll
    for (int mi = 0; mi < 4; mi++)
#pragma unroll
      for (int ni = 0; ni < 4; ni++)
        acc[mi][ni] = __builtin_amdgcn_mfma_f32_16x16x32_f16(af[mi], bfr[ni], acc[mi][ni], 0, 0, 0);
  }

#pragma unroll
  for (int mi = 0; mi < 4; mi++)
#pragma unroll
    for (int r = 0; r < 4; r++) {
      int qc = q0 + wm * 64 + mi * 16 + quad * 4 + r;
      if (qc < cb) {
#pragma unroll
        for (int ni = 0; ni < 4; ni++) {
          int gt = t0 + wn * 64 + ni * 16 + l16;
          SC[((size_t)b * SEQ + qc) * SEQ + gt] = f2h_bits(acc[mi][ni][r]);
        }
      }
    }
}

// =============================================================================
// softmax on compacted rows: fp16 scores -> fp16 (softmax * NORM * ASCALE).
// =============================================================================
__global__ __launch_bounds__(256) void softmax_kernel(
    unsigned short* __restrict__ SC, const int* __restrict__ cnt) {
  int b = blockIdx.x >> 11, qc = blockIdx.x & 2047;
  if (qc >= cnt[b]) return;
  unsigned short* p = SC + ((size_t)b * SEQ + qc) * SEQ;
  int tid = threadIdx.x;

  short8 hv = *(const short8*)(p + (tid << 3));
  float v[8];
#pragma unroll
  for (int j = 0; j < 8; j++) v[j] = h2f_bits((unsigned short)hv[j]);

  float m = v[0];
#pragma unroll
  for (int j = 1; j < 8; j++) m = fmaxf(m, v[j]);
#pragma unroll
  for (int off = 32; off >= 1; off >>= 1) m = fmaxf(m, __shfl_down(m, off));

  __shared__ float red[8];
  int w = tid >> 6;
  if ((tid & 63) == 0) red[w] = m;
  __syncthreads();
  m = fmaxf(fmaxf(red[0], red[1]), fmaxf(red[2], red[3]));

  float e[8], s = 0.f;
#pragma unroll
  for (int j = 0; j < 8; j++) { e[j] = __expf(v[j] - m); s += e[j]; }
#pragma unroll
  for (int off = 32; off >= 1; off >>= 1) s += __shfl_down(s, off);
  if ((tid & 63) == 0) red[4 + w] = s;
  __syncthreads();
  float L = red[4] + red[5] + red[6] + red[7];

  float scale = NORM_F * ASCALE / L;   // ASCALE undone in pv epilogue
  short8 ov;
#pragma unroll
  for (int j = 0; j < 8; j++) ov[j] = (short)f2h_bits(e[j] * scale);
  *(short8*)(p + (tid << 3)) = ov;
}

// =============================================================================
// fill: masked rows get NORM * mean(V).
// =============================================================================
__global__ __launch_bounds__(256) void fill_kernel(
    const int* __restrict__ mask, const float* __restrict__ Vmean,
    float* __restrict__ out) {
  int row = blockIdx.x;
  if (mask[row] != 0) return;
  const float* vm = Vmean + (row >> 11) * DB;
  float* o = out + (size_t)row * DB;
  for (int n = threadIdx.x; n < DB; n += 256) o[n] = vm[n] * NORM_F;
}

// =============================================================================
// pv (compacted): out[idx[qc]][v] = (1/ASCALE) * sum_t attn[qc][t] * V[t][v].
// Same staging.  XCD swizzle: xcd g owns batch g (VT(b) L2-resident).
// =============================================================================
__global__ __launch_bounds__(256) void pv_kernel(
    const unsigned short* __restrict__ SC, const unsigned short* __restrict__ VT,
    const int* __restrict__ idx, const int* __restrict__ cnt,
    float* __restrict__ out) {
  __shared__ __align__(16) unsigned short As[8192], Bs[8192];
  int L = blockIdx.x;
  int b = L & 7, tt = L >> 3;                 // 768 blocks: 96 per xcd
  int q0 = (tt / 6) << 7;                     // q outer
  int v0 = (tt % 6) << 7;                     // v inner (SC stripe reused 6x)
  int cb = cnt[b];
  if (q0 >= cb) return;
  int tid = threadIdx.x;
  int wave = tid >> 6, lane = tid & 63;
  int wm = wave & 1, wn = wave >> 1;
  int quad = lane >> 4, l16 = lane & 15;
  int srow = ((wave & 1) << 6) | lane;
  int coff = (wave >> 1) * 8;

  const unsigned short* pA = SC + ((size_t)b * SEQ + q0 + srow) * SEQ + coff;  // rows>=cb: garbage, guarded
  const unsigned short* pB = VT + ((size_t)b * DB + v0 + srow) * SEQ + coff;
  unsigned short* lA = (unsigned short*)((char*)As + wave * 1024 + lane * 16);
  unsigned short* lB = (unsigned short*)((char*)Bs + wave * 1024 + lane * 16);

  f32x4 acc[4][4];
#pragma unroll
  for (int mi = 0; mi < 4; mi++)
#pragma unroll
    for (int ni = 0; ni < 4; ni++) acc[mi][ni] = (f32x4){0.f, 0.f, 0.f, 0.f};

  short8 va[2], vb[2];
  auto gld = [&](int kt) {
    va[0] = *(const short8*)(pA + kt);  va[1] = *(const short8*)(pA + kt + 16);
    vb[0] = *(const short8*)(pB + kt);  vb[1] = *(const short8*)(pB + kt + 16);
  };

  gld(0);
  for (int it = 0; it < 64; it++) {
    __syncthreads();
    *(short8*)lA = va[0];  *(short8*)(lA + 2048) = va[1];
    *(short8*)lB = vb[0];  *(short8*)(lB + 2048) = vb[1];
    __syncthreads();
    if (it < 63) gld((it + 1) * 32);

    half8 af[4], bfr[4];
#pragma unroll
    for (int mi = 0; mi < 4; mi++)
      af[mi] = *(const half8*)&As[quad * 1024 + (wm * 64 + mi * 16 + l16) * 8];
#pragma unroll
    for (int ni = 0; ni < 4; ni++)
      bfr[ni] = *(const half8*)&Bs[quad * 1024 + (wn * 64 + ni * 16 + l16) * 8];
#pragma unroll
    for (int mi = 0; mi < 4; mi++)
#pragma unroll
      for (int ni = 0; ni < 4; ni++)
        acc[mi][ni] = __builtin_amdgcn_mfma_f32_16x16x32_f16(af[mi], bfr[ni], acc[mi][ni], 0, 0, 0);
  }

#pragma unroll
  for (int mi = 0; mi < 4; mi++)
#pragma unroll
    for (int r = 0; r < 4; r++) {
      int qc = q0 + wm * 64 + mi * 16 + quad * 4 + r;
      if (qc < cb) {
        int q = idx[b * SEQ + qc];
#pragma unroll
        for (int ni = 0; ni < 4; ni++) {
          int gv = v0 + wn * 64 + ni * 16 + l16;
          out[((size_t)b * SEQ + q) * DB + gv] = acc[mi][ni][r] * INV_ASCALE;
        }
      }
    }
}

// =============================================================================
extern "C" void kernel_launch(void* const* d_in, const int* in_sizes, int n_in,
                              void* d_out, int out_size, void* d_ws, size_t ws_size,
                              hipStream_t stream) {
  const float* x    = (const float*)d_in[0];
  const int*   mask = (const int*)d_in[1];
  const float* Wq   = (const float*)d_in[2];
  const float* bq   = (const float*)d_in[3];
  const float* Wk   = (const float*)d_in[4];
  const float* bk   = (const float*)d_in[5];
  const float* Wv   = (const float*)d_in[6];
  const float* bv   = (const float*)d_in[7];
  float* out = (float*)d_out;
  char* ws = (char*)d_ws;

  // Workspace (~143 MB). SC region [0, 67.1MB) also hosts Xf/WT, which die
  // when proj completes; scores then overwrites with SC.
  const size_t TOKH = (size_t)NTOK * DB * 2;                 // 25,165,824 B
  unsigned short* SC = (unsigned short*)ws;
  unsigned short* Xf = (unsigned short*)ws;
  unsigned short* WT = (unsigned short*)(ws + TOKH);
  const size_t SCSZ = (size_t)BATCH * SEQ * SEQ * 2;         // 67,108,864 B
  unsigned short* Qf = (unsigned short*)(ws + SCSZ);
  unsigned short* Kf = Qf + (size_t)NTOK * DB;
  unsigned short* VT = Kf + (size_t)NTOK * DB;
  int*   idx   = (int*)(ws + SCSZ + 3 * TOKH);
  int*   cnt   = idx + NTOK;
  float* Vmean = (float*)(cnt + 16);

  whalf_kernel<<<432, 256, 0, stream>>>(Wq, Wk, Wv, WT);
  xhalf_kernel<<<NTOK * DB / 2048, 256, 0, stream>>>(x, Xf);
  compact_kernel<<<BATCH, 256, 0, stream>>>(mask, idx, cnt);
  proj_kernel<<<NFUSE / 128 * (NTOK / 128), 256, 0, stream>>>(
      Xf, WT, bq, bk, bv, Qf, Kf, VT);
  vmean_kernel<<<BATCH * DB, 256, 0, stream>>>(VT, Vmean);
  scores_kernel<<<(SEQ / 128) * (SEQ / 128) * BATCH, 256, 0, stream>>>(
      Qf, Kf, idx, cnt, SC);
  softmax_kernel<<<NTOK, 256, 0, stream>>>(SC, cnt);
  fill_kernel<<<NTOK, 256, 0, stream>>>(mask, Vmean, out);
  pv_kernel<<<(DB / 128) * (SEQ / 128) * BATCH, 256, 0, stream>>>(
      SC, VT, idx, cnt, out);
}